// Round 11
// baseline (242.759 us; speedup 1.0000x reference)
//
#include <hip/hip_runtime.h>
#include <hip/hip_bf16.h>
#include <math.h>

// Problem constants
constexpr int Bn     = 16;    // batch
constexpr int Cc     = 384;   // channels
constexpr int Nn     = 1024;  // tokens (32*32)
constexpr int NHEADS = 8;
constexpr int HD     = 48;    // head dim
constexpr float SCALE = 0.14433756729740643f; // 48^-0.5
constexpr float SCL2  = 0.14433756729740643f * 1.4426950408889634f; // SCALE*log2(e)

using bf16x8 = __attribute__((ext_vector_type(8))) short;
using bf16x4 = __attribute__((ext_vector_type(4))) short;
using f32x4  = __attribute__((ext_vector_type(4))) float;

__device__ inline short f2b(float f) {
    __hip_bfloat16 h = __float2bfloat16(f);
    return *reinterpret_cast<short*>(&h);
}
__device__ inline float b2f(short s) {
    __hip_bfloat16 h = *reinterpret_cast<__hip_bfloat16*>(&s);
    return __bfloat162float(h);
}

// ---------------------------------------------------------------------------
// Elementwise fp32 -> (hi, lo) bf16 split.
// ---------------------------------------------------------------------------
__global__ __launch_bounds__(256) void conv_split(const float* __restrict__ in,
                                                  short* __restrict__ hi,
                                                  short* __restrict__ lo, int n)
{
    int i = (blockIdx.x * 256 + threadIdx.x) * 4;
    if (i >= n) return;
    float4 v = *reinterpret_cast<const float4*>(&in[i]);
    float vs[4] = {v.x, v.y, v.z, v.w};
    bf16x4 h, l;
#pragma unroll
    for (int j = 0; j < 4; ++j) {
        h[j] = f2b(vs[j]);
        l[j] = f2b(vs[j] - b2f(h[j]));
    }
    *reinterpret_cast<bf16x4*>(&hi[i]) = h;
    *reinterpret_cast<bf16x4*>(&lo[i]) = l;
}

// ---------------------------------------------------------------------------
// x (B, C, N) fp32 -> x^T (B, N, C) bf16 hi/lo.  64x64 tile via LDS.
// ---------------------------------------------------------------------------
__global__ __launch_bounds__(256) void prep_xt(const float* __restrict__ x,
                                               short* __restrict__ xt_hi,
                                               short* __restrict__ xt_lo)
{
    const int b  = blockIdx.z;
    const int c0 = blockIdx.y * 64;
    const int n0 = blockIdx.x * 64;
    __shared__ float T[64 * 68];

    const int tid = threadIdx.x;
    const int r   = tid >> 2;
    const int seg = tid & 3;

    const float* xb = x + ((size_t)b * Cc + c0) * Nn;
#pragma unroll
    for (int i = 0; i < 4; ++i) {
        float4 v = *reinterpret_cast<const float4*>(&xb[(size_t)r * Nn + n0 + seg * 16 + i * 4]);
        *reinterpret_cast<float4*>(&T[r * 68 + seg * 16 + i * 4]) = v;
    }
    __syncthreads();

    short* oh = xt_hi + ((size_t)b * Nn + n0 + r) * Cc + c0;
    short* ol = xt_lo + ((size_t)b * Nn + n0 + r) * Cc + c0;
#pragma unroll
    for (int i = 0; i < 4; ++i) {
        bf16x4 hv, lv;
#pragma unroll
        for (int j = 0; j < 4; ++j) {
            float v = T[(seg * 16 + i * 4 + j) * 68 + r];
            hv[j] = f2b(v);
            lv[j] = f2b(v - b2f(hv[j]));
        }
        *reinterpret_cast<bf16x4*>(&oh[seg * 16 + i * 4]) = hv;
        *reinterpret_cast<bf16x4*>(&ol[seg * 16 + i * 4]) = lv;
    }
}

// ---------------------------------------------------------------------------
// Split-bf16 MFMA GEMM: Y[b][m][n] = sum_k W[m][k] * X[b][n][k]
// MODE 0 (QKV): m<768 -> Yqk token-major (B,N,768) bf16 (Q rows pre-scaled by
//               SCL2); m>=768 -> Yv (B,384,N) bf16
// MODE 1 (PROJ): Yf fp32 (B,384,N) + bias
// ---------------------------------------------------------------------------
template <int MODE>
__global__ __launch_bounds__(256) void gemm_split(const short* __restrict__ Whi,
                                                  const short* __restrict__ Wlo,
                                                  const short* __restrict__ Xhi,
                                                  const short* __restrict__ Xlo,
                                                  short* __restrict__ Yqk,
                                                  short* __restrict__ Yv,
                                                  float* __restrict__ Yf,
                                                  const float* __restrict__ bias,
                                                  int M, int K, int NN)
{
    const int b  = blockIdx.z;
    const int m0 = blockIdx.y * 128;
    const int n0 = blockIdx.x * 128;
    const short* Xb_hi = Xhi + (size_t)b * NN * K;
    const short* Xb_lo = Xlo + (size_t)b * NN * K;

    __shared__ __align__(16) short smem[4 * 128 * 40];
    short* As_hi = smem;
    short* As_lo = smem + 5120;
    short* Bs_hi = smem + 10240;
    short* Bs_lo = smem + 15360;

    const int tid  = threadIdx.x;
    const int lane = tid & 63;
    const int wave = tid >> 6;
    const int c    = lane & 15;
    const int h4   = lane >> 4;
    const int wr   = wave >> 1;
    const int wc   = wave & 1;

    const int srow  = tid >> 1;
    const int skoff = (tid & 1) * 16;

    f32x4 acc[4][4];
#pragma unroll
    for (int mi = 0; mi < 4; ++mi)
#pragma unroll
        for (int ni = 0; ni < 4; ++ni) acc[mi][ni] = 0.0f;

    for (int k0 = 0; k0 < K; k0 += 32) {
        __syncthreads();
        {
            const size_t wrow = (size_t)(m0 + srow) * K + k0 + skoff;
            const size_t xrow = (size_t)(n0 + srow) * K + k0 + skoff;
            bf16x8 a0 = *reinterpret_cast<const bf16x8*>(&Whi[wrow]);
            bf16x8 a1 = *reinterpret_cast<const bf16x8*>(&Whi[wrow + 8]);
            bf16x8 a2 = *reinterpret_cast<const bf16x8*>(&Wlo[wrow]);
            bf16x8 a3 = *reinterpret_cast<const bf16x8*>(&Wlo[wrow + 8]);
            bf16x8 b0 = *reinterpret_cast<const bf16x8*>(&Xb_hi[xrow]);
            bf16x8 b1 = *reinterpret_cast<const bf16x8*>(&Xb_hi[xrow + 8]);
            bf16x8 b2 = *reinterpret_cast<const bf16x8*>(&Xb_lo[xrow]);
            bf16x8 b3 = *reinterpret_cast<const bf16x8*>(&Xb_lo[xrow + 8]);
            *reinterpret_cast<bf16x8*>(&As_hi[srow * 40 + skoff])     = a0;
            *reinterpret_cast<bf16x8*>(&As_hi[srow * 40 + skoff + 8]) = a1;
            *reinterpret_cast<bf16x8*>(&As_lo[srow * 40 + skoff])     = a2;
            *reinterpret_cast<bf16x8*>(&As_lo[srow * 40 + skoff + 8]) = a3;
            *reinterpret_cast<bf16x8*>(&Bs_hi[srow * 40 + skoff])     = b0;
            *reinterpret_cast<bf16x8*>(&Bs_hi[srow * 40 + skoff + 8]) = b1;
            *reinterpret_cast<bf16x8*>(&Bs_lo[srow * 40 + skoff])     = b2;
            *reinterpret_cast<bf16x8*>(&Bs_lo[srow * 40 + skoff + 8]) = b3;
        }
        __syncthreads();

        bf16x8 a_hi[4], a_lo[4], b_hi[4], b_lo[4];
#pragma unroll
        for (int mi = 0; mi < 4; ++mi) {
            a_hi[mi] = *reinterpret_cast<const bf16x8*>(&As_hi[(wr * 64 + mi * 16 + c) * 40 + h4 * 8]);
            a_lo[mi] = *reinterpret_cast<const bf16x8*>(&As_lo[(wr * 64 + mi * 16 + c) * 40 + h4 * 8]);
        }
#pragma unroll
        for (int ni = 0; ni < 4; ++ni) {
            b_hi[ni] = *reinterpret_cast<const bf16x8*>(&Bs_hi[(wc * 64 + ni * 16 + c) * 40 + h4 * 8]);
            b_lo[ni] = *reinterpret_cast<const bf16x8*>(&Bs_lo[(wc * 64 + ni * 16 + c) * 40 + h4 * 8]);
        }
#pragma unroll
        for (int mi = 0; mi < 4; ++mi)
#pragma unroll
            for (int ni = 0; ni < 4; ++ni) {
                acc[mi][ni] = __builtin_amdgcn_mfma_f32_16x16x32_bf16(a_hi[mi], b_hi[ni], acc[mi][ni], 0, 0, 0);
                acc[mi][ni] = __builtin_amdgcn_mfma_f32_16x16x32_bf16(a_hi[mi], b_lo[ni], acc[mi][ni], 0, 0, 0);
                acc[mi][ni] = __builtin_amdgcn_mfma_f32_16x16x32_bf16(a_lo[mi], b_hi[ni], acc[mi][ni], 0, 0, 0);
            }
    }

    if (MODE == 0) {
        if (m0 < 768) {
            // Q/K: token-major bf16 out; Q rows pre-scaled by SCL2
            const float qscale = (m0 < 384) ? SCL2 : 1.0f;
            __syncthreads();
            short* Cs = smem;  // [128 n][136]
#pragma unroll
            for (int mi = 0; mi < 4; ++mi)
#pragma unroll
                for (int ni = 0; ni < 4; ++ni) {
                    int nl = wc * 64 + ni * 16 + c;
                    int cl = wr * 64 + mi * 16 + 4 * h4;
                    bf16x4 pk;
#pragma unroll
                    for (int r = 0; r < 4; ++r) pk[r] = f2b(acc[mi][ni][r] * qscale);
                    *reinterpret_cast<bf16x4*>(&Cs[nl * 136 + cl]) = pk;
                }
            __syncthreads();
            // full 128x128 tile: 2048 b128 units, 8 per thread
#pragma unroll
            for (int l = 0; l < 8; ++l) {
                int u  = tid + l * 256;        // 0..2047
                int nl = u >> 4, ch = u & 15;  // nl 0..127, ch 0..15
                *reinterpret_cast<bf16x8*>(&Yqk[((size_t)b * NN + n0 + nl) * 768 + m0 + ch * 8]) =
                    *reinterpret_cast<const bf16x8*>(&Cs[nl * 136 + ch * 8]);
            }
        } else {
            // V: channel-major bf16 out (d, n) for PV frag loads
            __syncthreads();
            short* Cs = smem;  // [128 ch][136]
#pragma unroll
            for (int mi = 0; mi < 4; ++mi)
#pragma unroll
                for (int ni = 0; ni < 4; ++ni)
#pragma unroll
                    for (int r = 0; r < 4; ++r) {
                        int ml = wr * 64 + mi * 16 + h4 * 4 + r;
                        int nl = wc * 64 + ni * 16 + c;
                        Cs[ml * 136 + nl] = f2b(acc[mi][ni][r]);
                    }
            __syncthreads();
            short* Yb = Yv + (size_t)b * Cc * NN;
            const int cseg = (tid & 1) * 64;
#pragma unroll
            for (int i = 0; i < 8; ++i)
                *reinterpret_cast<bf16x8*>(&Yb[(size_t)(m0 - 768 + srow) * NN + n0 + cseg + i * 8]) =
                    *reinterpret_cast<const bf16x8*>(&Cs[srow * 136 + cseg + i * 8]);
        }
    } else {
        // PROJ: fp32 out + bias
        float* Yb = Yf + (size_t)b * M * NN;
        float* Cf = reinterpret_cast<float*>(smem);
        const int mr2 = tid >> 2;
        const int seg = tid & 3;
#pragma unroll
        for (int half = 0; half < 2; ++half) {
            __syncthreads();
            if (wr == half) {
#pragma unroll
                for (int mi = 0; mi < 4; ++mi)
#pragma unroll
                    for (int ni = 0; ni < 4; ++ni)
#pragma unroll
                        for (int r = 0; r < 4; ++r) {
                            int ml = mi * 16 + h4 * 4 + r;
                            int nl = wc * 64 + ni * 16 + c;
                            Cf[ml * 132 + nl] = acc[mi][ni][r];
                        }
            }
            __syncthreads();
            float bv = bias ? bias[m0 + half * 64 + mr2] : 0.0f;
#pragma unroll
            for (int i = 0; i < 8; ++i) {
                float4 v = *reinterpret_cast<const float4*>(&Cf[mr2 * 132 + seg * 32 + i * 4]);
                v.x += bv; v.y += bv; v.z += bv; v.w += bv;
                *reinterpret_cast<float4*>(&Yb[(size_t)(m0 + half * 64 + mr2) * NN + n0 + seg * 32 + i * 4]) = v;
            }
        }
    }
}

// ---------------------------------------------------------------------------
// LDS-free MFMA flash attention (flat, spill-proof, high-occupancy).
// Block = (b, head, 128-q tile), 4 waves, each wave owns 32 q (2 sets of 16).
// Grid = 1024 blocks = 4 blocks/CU = 16 waves/CU (fixes R9's grid-limited
// occupancy of 2 blocks/CU).
// Per tile: [load K frags] -> QK^T + softmax + pack P (2 sets) ->
//           [K dead, load V frags] -> PV (2 sets).
//   QK^T: A=K, B=Q -> lane (c,h4) holds S[q=qb+set*16+c][m=16j+4h4+r]
//   PV  : A=V, B=P, same sigma k-permutation on both operands
// lsum reduced across h4-slices via shfl_xor(16/32) once at the end.
// ---------------------------------------------------------------------------
__global__ __launch_bounds__(256, 2) void attn_mfma(const short* __restrict__ qk_t,
                                                    const short* __restrict__ v_cn,
                                                    short* __restrict__ aot_hi,
                                                    short* __restrict__ aot_lo)
{
    const int b  = blockIdx.z;
    const int h  = blockIdx.y;
    const int n0 = blockIdx.x * 128;

    const int tid  = threadIdx.x;
    const int lane = tid & 63;
    const int wave = tid >> 6;
    const int c    = lane & 15;
    const int h4   = lane >> 4;
    const int qb   = n0 + wave * 32;

    const short* Qb = qk_t + ((size_t)b * Nn + qb) * 768 + h * HD;
    const short* Kb = qk_t + (size_t)b * Nn * 768 + 384 + h * HD;
    const short* Vb = v_cn + ((size_t)b * Cc + h * HD) * Nn;

    const bf16x8 z8 = {};

    // ---- Q fragments (loop-invariant, 2 sets) ----
    bf16x8 qf0[2], qf1[2];
#pragma unroll
    for (int s = 0; s < 2; ++s) {
        const short* qrow = Qb + (size_t)(s * 16 + c) * 768;
        qf0[s] = *reinterpret_cast<const bf16x8*>(qrow + 8 * h4);
        qf1[s] = (h4 < 2) ? *reinterpret_cast<const bf16x8*>(qrow + 32 + 8 * h4) : z8;
    }

    f32x4 o[2][3];
#pragma unroll
    for (int s = 0; s < 2; ++s)
#pragma unroll
        for (int jd = 0; jd < 3; ++jd) o[s][jd] = 0.0f;
    float lsum[2] = {0.0f, 0.0f};

    for (int t = 0; t < 16; ++t) {
        const int m0 = t * 64;

        // ---- K fragments for this tile ----
        bf16x8 kc0[4], kc1[4];
#pragma unroll
        for (int j = 0; j < 4; ++j) {
            const short* krow = Kb + (size_t)(m0 + 16 * j + c) * 768;
            kc0[j] = *reinterpret_cast<const bf16x8*>(krow + 8 * h4);
            kc1[j] = (h4 < 2) ? *reinterpret_cast<const bf16x8*>(krow + 32 + 8 * h4) : z8;
        }

        // ---- QK^T + softmax + pack P, 2 sets ----
        bf16x8 pa[2][2];
#pragma unroll
        for (int set = 0; set < 2; ++set) {
            f32x4 s4[4];
#pragma unroll
            for (int j = 0; j < 4; ++j) s4[j] = 0.0f;
#pragma unroll
            for (int j = 0; j < 4; ++j) {
                s4[j] = __builtin_amdgcn_mfma_f32_16x16x32_bf16(kc0[j], qf0[set], s4[j], 0, 0, 0);
                s4[j] = __builtin_amdgcn_mfma_f32_16x16x32_bf16(kc1[j], qf1[set], s4[j], 0, 0, 0);
            }
            float p[4][4];
#pragma unroll
            for (int j = 0; j < 4; ++j)
#pragma unroll
                for (int r = 0; r < 4; ++r) {
                    p[j][r] = exp2f(s4[j][r]);
                    lsum[set] += p[j][r];
                }
#pragma unroll
            for (int r = 0; r < 4; ++r) {
                pa[set][0][r]     = f2b(p[0][r]);
                pa[set][0][4 + r] = f2b(p[1][r]);
                pa[set][1][r]     = f2b(p[2][r]);
                pa[set][1][4 + r] = f2b(p[3][r]);
            }
        }

        // ---- V fragments (K registers dead now) ----
        bf16x8 vf0[3], vf1[3];
#pragma unroll
        for (int jd = 0; jd < 3; ++jd) {
            const short* vrow = Vb + (size_t)(16 * jd + c) * Nn + m0;
            bf16x4 a0 = *reinterpret_cast<const bf16x4*>(vrow + 4 * h4);
            bf16x4 d0 = *reinterpret_cast<const bf16x4*>(vrow + 16 + 4 * h4);
            bf16x4 a1 = *reinterpret_cast<const bf16x4*>(vrow + 32 + 4 * h4);
            bf16x4 d1 = *reinterpret_cast<const bf16x4*>(vrow + 48 + 4 * h4);
            bf16x8 w0, w1;
#pragma unroll
            for (int r = 0; r < 4; ++r) {
                w0[r] = a0[r]; w0[4 + r] = d0[r];
                w1[r] = a1[r]; w1[4 + r] = d1[r];
            }
            vf0[jd] = w0;
            vf1[jd] = w1;
        }

        // ---- PV, 2 sets ----
#pragma unroll
        for (int set = 0; set < 2; ++set)
#pragma unroll
            for (int jd = 0; jd < 3; ++jd) {
                o[set][jd] = __builtin_amdgcn_mfma_f32_16x16x32_bf16(vf0[jd], pa[set][0], o[set][jd], 0, 0, 0);
                o[set][jd] = __builtin_amdgcn_mfma_f32_16x16x32_bf16(vf1[jd], pa[set][1], o[set][jd], 0, 0, 0);
            }
    }

    // ---- epilogue: reduce lsum across h4 slices, normalize, split hi/lo ----
#pragma unroll
    for (int set = 0; set < 2; ++set) {
        lsum[set] += __shfl_xor(lsum[set], 16);
        lsum[set] += __shfl_xor(lsum[set], 32);
        float linv = 1.0f / lsum[set];
        size_t rowoff = ((size_t)b * Nn + qb + set * 16 + c) * Cc + h * HD;
#pragma unroll
        for (int jd = 0; jd < 3; ++jd) {
            bf16x4 hv, lv;
#pragma unroll
            for (int r = 0; r < 4; ++r) {
                float val = o[set][jd][r] * linv;
                short x = f2b(val);
                hv[r] = x;
                lv[r] = f2b(val - b2f(x));
            }
            *reinterpret_cast<bf16x4*>(&aot_hi[rowoff + 16 * jd + 4 * h4]) = hv;
            *reinterpret_cast<bf16x4*>(&aot_lo[rowoff + 16 * jd + 4 * h4]) = lv;
        }
    }
}

// ---------------------------------------------------------------------------
extern "C" void kernel_launch(void* const* d_in, const int* in_sizes, int n_in,
                              void* d_out, int out_size, void* d_ws, size_t ws_size,
                              hipStream_t stream)
{
    const float* x      = (const float*)d_in[0];
    const float* w_qkv  = (const float*)d_in[1];
    const float* w_proj = (const float*)d_in[2];
    const float* b_proj = (const float*)d_in[3];
    float* out = (float*)d_out;

    short* ws = (short*)d_ws;
    const size_t XT = (size_t)Bn * Nn * Cc;            // 6291456
    short* xt_hi  = ws;
    short* xt_lo  = xt_hi + XT;
    short* wq_hi  = xt_lo + XT;
    short* wq_lo  = wq_hi + (size_t)3 * Cc * Cc;
    short* wp_hi  = wq_lo + (size_t)3 * Cc * Cc;
    short* wp_lo  = wp_hi + (size_t)Cc * Cc;
    short* qk_t   = wp_lo + (size_t)Cc * Cc;           // (B, N, 768)
    short* v_cn   = qk_t + (size_t)Bn * Nn * 768;      // (B, 384, N)
    short* aot_hi = v_cn + XT;
    short* aot_lo = aot_hi + XT;

    // 0) weight + x prep
    conv_split<<<(3 * Cc * Cc / 4 + 255) / 256, 256, 0, stream>>>(w_qkv, wq_hi, wq_lo, 3 * Cc * Cc);
    conv_split<<<(Cc * Cc / 4 + 255) / 256, 256, 0, stream>>>(w_proj, wp_hi, wp_lo, Cc * Cc);
    prep_xt<<<dim3(Nn / 64, Cc / 64, Bn), 256, 0, stream>>>(x, xt_hi, xt_lo);

    // 1) QKV GEMM -> qk_t (token-major Q,K; Q pre-scaled) + v_cn (channel-major V)
    gemm_split<0><<<dim3(Nn / 128, (3 * Cc) / 128, Bn), 256, 0, stream>>>(
        wq_hi, wq_lo, xt_hi, xt_lo, qk_t, v_cn, nullptr, nullptr, 3 * Cc, Cc, Nn);

    // 2) LDS-free MFMA flash attention (2 sets/wave, 1024 blocks)
    attn_mfma<<<dim3(Nn / 128, NHEADS, Bn), 256, 0, stream>>>(qk_t, v_cn, aot_hi, aot_lo);

    // 3) Projection GEMM (fp32 out + bias)
    gemm_split<1><<<dim3(Nn / 128, Cc / 128, Bn), 256, 0, stream>>>(
        wp_hi, wp_lo, aot_hi, aot_lo, nullptr, nullptr, out, b_proj, Cc, Cc, Nn);
}

// Round 12
// 165.348 us; speedup vs baseline: 1.4682x; 1.4682x over previous
//
#include <hip/hip_runtime.h>
#include <hip/hip_bf16.h>
#include <math.h>

// Problem constants
constexpr int Bn     = 16;    // batch
constexpr int Cc     = 384;   // channels
constexpr int Nn     = 1024;  // tokens (32*32)
constexpr int NHEADS = 8;
constexpr int HD     = 48;    // head dim
constexpr float SCALE = 0.14433756729740643f; // 48^-0.5
constexpr float SCL2  = 0.14433756729740643f * 1.4426950408889634f; // SCALE*log2(e)

using bf16x8 = __attribute__((ext_vector_type(8))) short;
using bf16x4 = __attribute__((ext_vector_type(4))) short;
using f32x4  = __attribute__((ext_vector_type(4))) float;

__device__ inline short f2b(float f) {
    __hip_bfloat16 h = __float2bfloat16(f);
    return *reinterpret_cast<short*>(&h);
}
__device__ inline float b2f(short s) {
    __hip_bfloat16 h = *reinterpret_cast<__hip_bfloat16*>(&s);
    return __bfloat162float(h);
}

// ---------------------------------------------------------------------------
// Elementwise fp32 -> (hi, lo) bf16 split.
// ---------------------------------------------------------------------------
__global__ __launch_bounds__(256) void conv_split(const float* __restrict__ in,
                                                  short* __restrict__ hi,
                                                  short* __restrict__ lo, int n)
{
    int i = (blockIdx.x * 256 + threadIdx.x) * 4;
    if (i >= n) return;
    float4 v = *reinterpret_cast<const float4*>(&in[i]);
    float vs[4] = {v.x, v.y, v.z, v.w};
    bf16x4 h, l;
#pragma unroll
    for (int j = 0; j < 4; ++j) {
        h[j] = f2b(vs[j]);
        l[j] = f2b(vs[j] - b2f(h[j]));
    }
    *reinterpret_cast<bf16x4*>(&hi[i]) = h;
    *reinterpret_cast<bf16x4*>(&lo[i]) = l;
}

// ---------------------------------------------------------------------------
// x (B, C, N) fp32 -> x^T (B, N, C) bf16 hi/lo.  64x64 tile via LDS.
// ---------------------------------------------------------------------------
__global__ __launch_bounds__(256) void prep_xt(const float* __restrict__ x,
                                               short* __restrict__ xt_hi,
                                               short* __restrict__ xt_lo)
{
    const int b  = blockIdx.z;
    const int c0 = blockIdx.y * 64;
    const int n0 = blockIdx.x * 64;
    __shared__ float T[64 * 68];

    const int tid = threadIdx.x;
    const int r   = tid >> 2;
    const int seg = tid & 3;

    const float* xb = x + ((size_t)b * Cc + c0) * Nn;
#pragma unroll
    for (int i = 0; i < 4; ++i) {
        float4 v = *reinterpret_cast<const float4*>(&xb[(size_t)r * Nn + n0 + seg * 16 + i * 4]);
        *reinterpret_cast<float4*>(&T[r * 68 + seg * 16 + i * 4]) = v;
    }
    __syncthreads();

    short* oh = xt_hi + ((size_t)b * Nn + n0 + r) * Cc + c0;
    short* ol = xt_lo + ((size_t)b * Nn + n0 + r) * Cc + c0;
#pragma unroll
    for (int i = 0; i < 4; ++i) {
        bf16x4 hv, lv;
#pragma unroll
        for (int j = 0; j < 4; ++j) {
            float v = T[(seg * 16 + i * 4 + j) * 68 + r];
            hv[j] = f2b(v);
            lv[j] = f2b(v - b2f(hv[j]));
        }
        *reinterpret_cast<bf16x4*>(&oh[seg * 16 + i * 4]) = hv;
        *reinterpret_cast<bf16x4*>(&ol[seg * 16 + i * 4]) = lv;
    }
}

// ---------------------------------------------------------------------------
// Split-bf16 MFMA GEMM: Y[b][m][n] = sum_k W[m][k] * X[b][n][k]
// MODE 0 (QKV): m<768 -> Yqk token-major (B,N,768) bf16 (Q rows pre-scaled by
//               SCL2); m>=768 -> Yv (B,384,N) bf16
// MODE 1 (PROJ): Yf fp32 (B,384,N) + bias
// ---------------------------------------------------------------------------
template <int MODE>
__global__ __launch_bounds__(256) void gemm_split(const short* __restrict__ Whi,
                                                  const short* __restrict__ Wlo,
                                                  const short* __restrict__ Xhi,
                                                  const short* __restrict__ Xlo,
                                                  short* __restrict__ Yqk,
                                                  short* __restrict__ Yv,
                                                  float* __restrict__ Yf,
                                                  const float* __restrict__ bias,
                                                  int M, int K, int NN)
{
    const int b  = blockIdx.z;
    const int m0 = blockIdx.y * 128;
    const int n0 = blockIdx.x * 128;
    const short* Xb_hi = Xhi + (size_t)b * NN * K;
    const short* Xb_lo = Xlo + (size_t)b * NN * K;

    __shared__ __align__(16) short smem[4 * 128 * 40];
    short* As_hi = smem;
    short* As_lo = smem + 5120;
    short* Bs_hi = smem + 10240;
    short* Bs_lo = smem + 15360;

    const int tid  = threadIdx.x;
    const int lane = tid & 63;
    const int wave = tid >> 6;
    const int c    = lane & 15;
    const int h4   = lane >> 4;
    const int wr   = wave >> 1;
    const int wc   = wave & 1;

    const int srow  = tid >> 1;
    const int skoff = (tid & 1) * 16;

    f32x4 acc[4][4];
#pragma unroll
    for (int mi = 0; mi < 4; ++mi)
#pragma unroll
        for (int ni = 0; ni < 4; ++ni) acc[mi][ni] = 0.0f;

    for (int k0 = 0; k0 < K; k0 += 32) {
        __syncthreads();
        {
            const size_t wrow = (size_t)(m0 + srow) * K + k0 + skoff;
            const size_t xrow = (size_t)(n0 + srow) * K + k0 + skoff;
            bf16x8 a0 = *reinterpret_cast<const bf16x8*>(&Whi[wrow]);
            bf16x8 a1 = *reinterpret_cast<const bf16x8*>(&Whi[wrow + 8]);
            bf16x8 a2 = *reinterpret_cast<const bf16x8*>(&Wlo[wrow]);
            bf16x8 a3 = *reinterpret_cast<const bf16x8*>(&Wlo[wrow + 8]);
            bf16x8 b0 = *reinterpret_cast<const bf16x8*>(&Xb_hi[xrow]);
            bf16x8 b1 = *reinterpret_cast<const bf16x8*>(&Xb_hi[xrow + 8]);
            bf16x8 b2 = *reinterpret_cast<const bf16x8*>(&Xb_lo[xrow]);
            bf16x8 b3 = *reinterpret_cast<const bf16x8*>(&Xb_lo[xrow + 8]);
            *reinterpret_cast<bf16x8*>(&As_hi[srow * 40 + skoff])     = a0;
            *reinterpret_cast<bf16x8*>(&As_hi[srow * 40 + skoff + 8]) = a1;
            *reinterpret_cast<bf16x8*>(&As_lo[srow * 40 + skoff])     = a2;
            *reinterpret_cast<bf16x8*>(&As_lo[srow * 40 + skoff + 8]) = a3;
            *reinterpret_cast<bf16x8*>(&Bs_hi[srow * 40 + skoff])     = b0;
            *reinterpret_cast<bf16x8*>(&Bs_hi[srow * 40 + skoff + 8]) = b1;
            *reinterpret_cast<bf16x8*>(&Bs_lo[srow * 40 + skoff])     = b2;
            *reinterpret_cast<bf16x8*>(&Bs_lo[srow * 40 + skoff + 8]) = b3;
        }
        __syncthreads();

        bf16x8 a_hi[4], a_lo[4], b_hi[4], b_lo[4];
#pragma unroll
        for (int mi = 0; mi < 4; ++mi) {
            a_hi[mi] = *reinterpret_cast<const bf16x8*>(&As_hi[(wr * 64 + mi * 16 + c) * 40 + h4 * 8]);
            a_lo[mi] = *reinterpret_cast<const bf16x8*>(&As_lo[(wr * 64 + mi * 16 + c) * 40 + h4 * 8]);
        }
#pragma unroll
        for (int ni = 0; ni < 4; ++ni) {
            b_hi[ni] = *reinterpret_cast<const bf16x8*>(&Bs_hi[(wc * 64 + ni * 16 + c) * 40 + h4 * 8]);
            b_lo[ni] = *reinterpret_cast<const bf16x8*>(&Bs_lo[(wc * 64 + ni * 16 + c) * 40 + h4 * 8]);
        }
#pragma unroll
        for (int mi = 0; mi < 4; ++mi)
#pragma unroll
            for (int ni = 0; ni < 4; ++ni) {
                acc[mi][ni] = __builtin_amdgcn_mfma_f32_16x16x32_bf16(a_hi[mi], b_hi[ni], acc[mi][ni], 0, 0, 0);
                acc[mi][ni] = __builtin_amdgcn_mfma_f32_16x16x32_bf16(a_hi[mi], b_lo[ni], acc[mi][ni], 0, 0, 0);
                acc[mi][ni] = __builtin_amdgcn_mfma_f32_16x16x32_bf16(a_lo[mi], b_hi[ni], acc[mi][ni], 0, 0, 0);
            }
    }

    if (MODE == 0) {
        if (m0 < 768) {
            // Q/K: token-major bf16 out; Q rows pre-scaled by SCL2
            const float qscale = (m0 < 384) ? SCL2 : 1.0f;
            __syncthreads();
            short* Cs = smem;  // [128 n][136]
#pragma unroll
            for (int mi = 0; mi < 4; ++mi)
#pragma unroll
                for (int ni = 0; ni < 4; ++ni) {
                    int nl = wc * 64 + ni * 16 + c;
                    int cl = wr * 64 + mi * 16 + 4 * h4;
                    bf16x4 pk;
#pragma unroll
                    for (int r = 0; r < 4; ++r) pk[r] = f2b(acc[mi][ni][r] * qscale);
                    *reinterpret_cast<bf16x4*>(&Cs[nl * 136 + cl]) = pk;
                }
            __syncthreads();
            // full 128x128 tile: 2048 b128 units, 8 per thread
#pragma unroll
            for (int l = 0; l < 8; ++l) {
                int u  = tid + l * 256;        // 0..2047
                int nl = u >> 4, ch = u & 15;  // nl 0..127, ch 0..15
                *reinterpret_cast<bf16x8*>(&Yqk[((size_t)b * NN + n0 + nl) * 768 + m0 + ch * 8]) =
                    *reinterpret_cast<const bf16x8*>(&Cs[nl * 136 + ch * 8]);
            }
        } else {
            // V: channel-major bf16 out (d, n)
            __syncthreads();
            short* Cs = smem;  // [128 ch][136]
#pragma unroll
            for (int mi = 0; mi < 4; ++mi)
#pragma unroll
                for (int ni = 0; ni < 4; ++ni)
#pragma unroll
                    for (int r = 0; r < 4; ++r) {
                        int ml = wr * 64 + mi * 16 + h4 * 4 + r;
                        int nl = wc * 64 + ni * 16 + c;
                        Cs[ml * 136 + nl] = f2b(acc[mi][ni][r]);
                    }
            __syncthreads();
            short* Yb = Yv + (size_t)b * Cc * NN;
            const int cseg = (tid & 1) * 64;
#pragma unroll
            for (int i = 0; i < 8; ++i)
                *reinterpret_cast<bf16x8*>(&Yb[(size_t)(m0 - 768 + srow) * NN + n0 + cseg + i * 8]) =
                    *reinterpret_cast<const bf16x8*>(&Cs[srow * 136 + cseg + i * 8]);
        }
    } else {
        // PROJ: fp32 out + bias
        float* Yb = Yf + (size_t)b * M * NN;
        float* Cf = reinterpret_cast<float*>(smem);
        const int mr2 = tid >> 2;
        const int seg = tid & 3;
#pragma unroll
        for (int half = 0; half < 2; ++half) {
            __syncthreads();
            if (wr == half) {
#pragma unroll
                for (int mi = 0; mi < 4; ++mi)
#pragma unroll
                    for (int ni = 0; ni < 4; ++ni)
#pragma unroll
                        for (int r = 0; r < 4; ++r) {
                            int ml = mi * 16 + h4 * 4 + r;
                            int nl = wc * 64 + ni * 16 + c;
                            Cf[ml * 132 + nl] = acc[mi][ni][r];
                        }
            }
            __syncthreads();
            float bv = bias ? bias[m0 + half * 64 + mr2] : 0.0f;
#pragma unroll
            for (int i = 0; i < 8; ++i) {
                float4 v = *reinterpret_cast<const float4*>(&Cf[mr2 * 132 + seg * 32 + i * 4]);
                v.x += bv; v.y += bv; v.z += bv; v.w += bv;
                *reinterpret_cast<float4*>(&Yb[(size_t)(m0 + half * 64 + mr2) * NN + n0 + seg * 32 + i * 4]) = v;
            }
        }
    }
}

// ---------------------------------------------------------------------------
// Hybrid MFMA flash attention: LDS-staged K/V (shared by all 4 waves, staged
// once per block-tile) + register-only P via sigma-permuted PV (no P LDS
// round-trip), Q frags hoisted from global.
// Block = (b, head, 128-q tile): 4 waves x 32 q (2 sets of 16). Grid 1024.
// LDS: Ks[64 m][72] (m, d: chunks 0..5 real, d>=48 never read);
//      Vs[48 d][72] sigma-ordered m (frag = single b128 at slot h4*8 / 32+h4*8)
// sigma(h4,e) = 32s + 16*(e>=4) + 4*h4 + (e&3); linear b128 of V maps to two
// contiguous b64 sigma chunks (derivation in journal).
//   QK^T: A=K(LDS), B=Q(regs) -> lane (c,h4): S[q=qb+set*16+c][m=16j+4h4+r]
//   PV  : A=V(LDS,sigma), B=P(regs,sigma) -> O[q=qb+set*16+c][d=16jd+4h4+r]
// lsum reduced across h4-slices via shfl_xor(16/32) once at the end.
// ---------------------------------------------------------------------------
__global__ __launch_bounds__(256, 4) void attn_mfma(const short* __restrict__ qk_t,
                                                    const short* __restrict__ v_cn,
                                                    short* __restrict__ aot_hi,
                                                    short* __restrict__ aot_lo)
{
    const int b  = blockIdx.z;
    const int h  = blockIdx.y;
    const int n0 = blockIdx.x * 128;

    __shared__ __align__(16) short smem[(64 + 48) * 72];
    short* Ks = smem;            // [64][72]
    short* Vs = smem + 64 * 72;  // [48][72] sigma

    const int tid  = threadIdx.x;
    const int lane = tid & 63;
    const int wave = tid >> 6;
    const int c    = lane & 15;
    const int h4   = lane >> 4;
    const int qb   = n0 + wave * 32;

    const short* Qb = qk_t + ((size_t)b * Nn + qb) * 768 + h * HD;
    const short* Kbase = qk_t + (size_t)b * Nn * 768 + 384 + h * HD;
    const short* Vb = v_cn + ((size_t)b * Cc + h * HD) * Nn;

    const bf16x8 z8 = {};

    // ---- Q fragments (loop-invariant, 2 sets) ----
    bf16x8 qf0[2], qf1[2];
#pragma unroll
    for (int s = 0; s < 2; ++s) {
        const short* qrow = Qb + (size_t)(s * 16 + c) * 768;
        qf0[s] = *reinterpret_cast<const bf16x8*>(qrow + 8 * h4);
        qf1[s] = (h4 < 2) ? *reinterpret_cast<const bf16x8*>(qrow + 32 + 8 * h4) : z8;
    }

    f32x4 o[2][3];
#pragma unroll
    for (int s = 0; s < 2; ++s)
#pragma unroll
        for (int jd = 0; jd < 3; ++jd) o[s][jd] = 0.0f;
    float lsum[2] = {0.0f, 0.0f};

    for (int t = 0; t < 16; ++t) {
        const int m0 = t * 64;
        __syncthreads();   // prev iteration's LDS reads done

        // ---- stage K: 64 rows x 6 chunks = 384 b128 units ----
#pragma unroll
        for (int l = 0; l < 2; ++l) {
            int u = tid + l * 256;          // 0..511
            int m = u >> 3, ch = u & 7;
            if (ch < 6)
                *reinterpret_cast<bf16x8*>(&Ks[m * 72 + ch * 8]) =
                    *reinterpret_cast<const bf16x8*>(&Kbase[(size_t)(m0 + m) * 768 + ch * 8]);
        }
        // ---- stage V into sigma layout: 48 rows x 8 chunks = 384 units ----
#pragma unroll
        for (int l = 0; l < 2; ++l) {
            int u = tid + l * 256;
            if (u < 384) {
                int d = u >> 3, uu = u & 7;
                bf16x8 x = *reinterpret_cast<const bf16x8*>(&Vb[(size_t)d * Nn + m0 + uu * 8]);
                int s  = uu >> 2, v = uu & 3;
                int base = 32 * s + 16 * (v & 1);
                int off0 = (v < 2) ? base : base + 4;
                bf16x4 lo = {x[0], x[1], x[2], x[3]};
                bf16x4 hi = {x[4], x[5], x[6], x[7]};
                *reinterpret_cast<bf16x4*>(&Vs[d * 72 + off0])     = lo;
                *reinterpret_cast<bf16x4*>(&Vs[d * 72 + off0 + 8]) = hi;
            }
        }
        __syncthreads();

        // ---- QK^T: K frags shared by both sets ----
        f32x4 s4a[4], s4b[4];
#pragma unroll
        for (int j = 0; j < 4; ++j) { s4a[j] = 0.0f; s4b[j] = 0.0f; }
#pragma unroll
        for (int j = 0; j < 4; ++j) {
            bf16x8 kc0 = *reinterpret_cast<const bf16x8*>(&Ks[(16 * j + c) * 72 + h4 * 8]);
            bf16x8 kc1 = (h4 < 2) ? *reinterpret_cast<const bf16x8*>(&Ks[(16 * j + c) * 72 + 32 + h4 * 8]) : z8;
            s4a[j] = __builtin_amdgcn_mfma_f32_16x16x32_bf16(kc0, qf0[0], s4a[j], 0, 0, 0);
            s4a[j] = __builtin_amdgcn_mfma_f32_16x16x32_bf16(kc1, qf1[0], s4a[j], 0, 0, 0);
            s4b[j] = __builtin_amdgcn_mfma_f32_16x16x32_bf16(kc0, qf0[1], s4b[j], 0, 0, 0);
            s4b[j] = __builtin_amdgcn_mfma_f32_16x16x32_bf16(kc1, qf1[1], s4b[j], 0, 0, 0);
        }

        // ---- softmax-lite + pack P (sigma order), both sets ----
        bf16x8 pa[2][2];
        {
            float p[4][4];
#pragma unroll
            for (int j = 0; j < 4; ++j)
#pragma unroll
                for (int r = 0; r < 4; ++r) {
                    p[j][r] = exp2f(s4a[j][r]);
                    lsum[0] += p[j][r];
                }
#pragma unroll
            for (int r = 0; r < 4; ++r) {
                pa[0][0][r]     = f2b(p[0][r]);
                pa[0][0][4 + r] = f2b(p[1][r]);
                pa[0][1][r]     = f2b(p[2][r]);
                pa[0][1][4 + r] = f2b(p[3][r]);
            }
        }
        {
            float p[4][4];
#pragma unroll
            for (int j = 0; j < 4; ++j)
#pragma unroll
                for (int r = 0; r < 4; ++r) {
                    p[j][r] = exp2f(s4b[j][r]);
                    lsum[1] += p[j][r];
                }
#pragma unroll
            for (int r = 0; r < 4; ++r) {
                pa[1][0][r]     = f2b(p[0][r]);
                pa[1][0][4 + r] = f2b(p[1][r]);
                pa[1][1][r]     = f2b(p[2][r]);
                pa[1][1][4 + r] = f2b(p[3][r]);
            }
        }

        // ---- PV: V frags from sigma LDS (single b128 each), shared by sets ----
#pragma unroll
        for (int jd = 0; jd < 3; ++jd) {
            bf16x8 vf0 = *reinterpret_cast<const bf16x8*>(&Vs[(16 * jd + c) * 72 + h4 * 8]);
            bf16x8 vf1 = *reinterpret_cast<const bf16x8*>(&Vs[(16 * jd + c) * 72 + 32 + h4 * 8]);
            o[0][jd] = __builtin_amdgcn_mfma_f32_16x16x32_bf16(vf0, pa[0][0], o[0][jd], 0, 0, 0);
            o[0][jd] = __builtin_amdgcn_mfma_f32_16x16x32_bf16(vf1, pa[0][1], o[0][jd], 0, 0, 0);
            o[1][jd] = __builtin_amdgcn_mfma_f32_16x16x32_bf16(vf0, pa[1][0], o[1][jd], 0, 0, 0);
            o[1][jd] = __builtin_amdgcn_mfma_f32_16x16x32_bf16(vf1, pa[1][1], o[1][jd], 0, 0, 0);
        }
    }

    // ---- epilogue: reduce lsum across h4 slices, normalize, split hi/lo ----
#pragma unroll
    for (int set = 0; set < 2; ++set) {
        lsum[set] += __shfl_xor(lsum[set], 16);
        lsum[set] += __shfl_xor(lsum[set], 32);
        float linv = 1.0f / lsum[set];
        size_t rowoff = ((size_t)b * Nn + qb + set * 16 + c) * Cc + h * HD;
#pragma unroll
        for (int jd = 0; jd < 3; ++jd) {
            bf16x4 hv, lv;
#pragma unroll
            for (int r = 0; r < 4; ++r) {
                float val = o[set][jd][r] * linv;
                short x = f2b(val);
                hv[r] = x;
                lv[r] = f2b(val - b2f(x));
            }
            *reinterpret_cast<bf16x4*>(&aot_hi[rowoff + 16 * jd + 4 * h4]) = hv;
            *reinterpret_cast<bf16x4*>(&aot_lo[rowoff + 16 * jd + 4 * h4]) = lv;
        }
    }
}

// ---------------------------------------------------------------------------
extern "C" void kernel_launch(void* const* d_in, const int* in_sizes, int n_in,
                              void* d_out, int out_size, void* d_ws, size_t ws_size,
                              hipStream_t stream)
{
    const float* x      = (const float*)d_in[0];
    const float* w_qkv  = (const float*)d_in[1];
    const float* w_proj = (const float*)d_in[2];
    const float* b_proj = (const float*)d_in[3];
    float* out = (float*)d_out;

    short* ws = (short*)d_ws;
    const size_t XT = (size_t)Bn * Nn * Cc;            // 6291456
    short* xt_hi  = ws;
    short* xt_lo  = xt_hi + XT;
    short* wq_hi  = xt_lo + XT;
    short* wq_lo  = wq_hi + (size_t)3 * Cc * Cc;
    short* wp_hi  = wq_lo + (size_t)3 * Cc * Cc;
    short* wp_lo  = wp_hi + (size_t)Cc * Cc;
    short* qk_t   = wp_lo + (size_t)Cc * Cc;           // (B, N, 768)
    short* v_cn   = qk_t + (size_t)Bn * Nn * 768;      // (B, 384, N)
    short* aot_hi = v_cn + XT;
    short* aot_lo = aot_hi + XT;

    // 0) weight + x prep
    conv_split<<<(3 * Cc * Cc / 4 + 255) / 256, 256, 0, stream>>>(w_qkv, wq_hi, wq_lo, 3 * Cc * Cc);
    conv_split<<<(Cc * Cc / 4 + 255) / 256, 256, 0, stream>>>(w_proj, wp_hi, wp_lo, Cc * Cc);
    prep_xt<<<dim3(Nn / 64, Cc / 64, Bn), 256, 0, stream>>>(x, xt_hi, xt_lo);

    // 1) QKV GEMM -> qk_t (token-major Q,K; Q pre-scaled) + v_cn (channel-major V)
    gemm_split<0><<<dim3(Nn / 128, (3 * Cc) / 128, Bn), 256, 0, stream>>>(
        wq_hi, wq_lo, xt_hi, xt_lo, qk_t, v_cn, nullptr, nullptr, 3 * Cc, Cc, Nn);

    // 2) Hybrid LDS + sigma-register attention (128q blocks, 1024 blocks)
    attn_mfma<<<dim3(Nn / 128, NHEADS, Bn), 256, 0, stream>>>(qk_t, v_cn, aot_hi, aot_lo);

    // 3) Projection GEMM (fp32 out + bias)
    gemm_split<1><<<dim3(Nn / 128, Cc / 128, Bn), 256, 0, stream>>>(
        wp_hi, wp_lo, aot_hi, aot_lo, nullptr, nullptr, out, b_proj, Cc, Cc, Nn);
}